// Round 7
// baseline (286.135 us; speedup 1.0000x reference)
//
#include <hip/hip_runtime.h>
#include <hip/hip_bf16.h>
#include <math.h>

// Problem constants
constexpr int kB  = 8;
constexpr int kT  = 1024;
constexpr int kC  = 768;
constexpr int kNH = 12;
constexpr int kHD = 64;
constexpr int kM  = kB * kT;        // 8192 rows
constexpr int k3C = 3 * kC;         // 2304
constexpr int k4C = 4 * kC;         // 3072

typedef __bf16 bf16x8 __attribute__((ext_vector_type(8)));
typedef float  f32x4  __attribute__((ext_vector_type(4)));
typedef unsigned short u16x8 __attribute__((ext_vector_type(8)));

__device__ inline void gload_lds16(const void* g, void* l) {
  // async global->LDS, 16B per lane; LDS dest = wave-uniform base + lane*16
  __builtin_amdgcn_global_load_lds(
      (const __attribute__((address_space(1))) void*)g,
      (__attribute__((address_space(3))) void*)l, 16, 0, 0);
}

// ---------------------------------------------------------------------------
// LayerNorm: one block (256 threads) per row of 768. fp32 in, bf16 out.
// ---------------------------------------------------------------------------
__global__ __launch_bounds__(256) void ln_kernel(
    const float* __restrict__ x, const float* __restrict__ g,
    const float* __restrict__ bta, __hip_bfloat16* __restrict__ out)
{
  __shared__ float red[4];
  int row = blockIdx.x;
  int tid = threadIdx.x;
  const float* xr = x + (size_t)row * kC;
  float v0 = xr[tid], v1 = xr[tid + 256], v2 = xr[tid + 512];

  float s = v0 + v1 + v2;
#pragma unroll
  for (int off = 32; off; off >>= 1) s += __shfl_xor(s, off);
  if ((tid & 63) == 0) red[tid >> 6] = s;
  __syncthreads();
  float mu = (red[0] + red[1] + red[2] + red[3]) * (1.0f / kC);

  float d0 = v0 - mu, d1 = v1 - mu, d2 = v2 - mu;
  float q = d0 * d0 + d1 * d1 + d2 * d2;
#pragma unroll
  for (int off = 32; off; off >>= 1) q += __shfl_xor(q, off);
  __syncthreads();
  if ((tid & 63) == 0) red[tid >> 6] = q;
  __syncthreads();
  float var = (red[0] + red[1] + red[2] + red[3]) * (1.0f / kC);
  float inv = rsqrtf(var + 1e-5f);

  __hip_bfloat16* orow = out + (size_t)row * kC;
  orow[tid]       = __float2bfloat16(d0 * inv * g[tid]       + bta[tid]);
  orow[tid + 256] = __float2bfloat16(d1 * inv * g[tid + 256] + bta[tid + 256]);
  orow[tid + 512] = __float2bfloat16(d2 * inv * g[tid + 512] + bta[tid + 512]);
}

// ---------------------------------------------------------------------------
// Weight transpose + cast: W[K][N] fp32 -> WT[N][K] bf16. 64x64 tiles.
// ---------------------------------------------------------------------------
__global__ __launch_bounds__(256) void transpose_cast(
    const float* __restrict__ W, __hip_bfloat16* __restrict__ WT, int K, int N)
{
  __shared__ __hip_bfloat16 t[64][65];
  int k0 = blockIdx.y * 64, n0 = blockIdx.x * 64;
  int tid = threadIdx.x;
#pragma unroll
  for (int it = 0; it < 16; ++it) {
    int e = it * 256 + tid;
    int r = e >> 6, c = e & 63;
    t[r][c] = __float2bfloat16(W[(size_t)(k0 + r) * N + n0 + c]);
  }
  __syncthreads();
#pragma unroll
  for (int it = 0; it < 16; ++it) {
    int e = it * 256 + tid;
    int nr = e >> 6, kc = e & 63;
    WT[(size_t)(n0 + nr) * K + k0 + kc] = t[kc][nr];
  }
}

// ---------------------------------------------------------------------------
// V transpose: qkv V-part [b][t][h][d] -> Vt[b][h][d][t]  (bf16)
// ---------------------------------------------------------------------------
__global__ __launch_bounds__(256) void v_transpose(
    const __hip_bfloat16* __restrict__ qkv, __hip_bfloat16* __restrict__ vt)
{
  __shared__ __hip_bfloat16 tile[64][80];   // row stride 160B (16B-aligned)
  int b = blockIdx.z, h = blockIdx.y, t0 = blockIdx.x * 64;
  int tid = threadIdx.x;
  const __hip_bfloat16* vb = qkv + (size_t)(b * kT) * k3C + 2 * kC + h * kHD;
#pragma unroll
  for (int it = 0; it < 2; ++it) {
    int e = it * 256 + tid;
    int r = e >> 3, c8 = (e & 7) * 8;
    *(u16x8*)&tile[r][c8] = *(const u16x8*)(vb + (size_t)(t0 + r) * k3C + c8);
  }
  __syncthreads();
  __hip_bfloat16* vrow = vt + (size_t)(b * kNH + h) * kHD * kT;
#pragma unroll
  for (int it = 0; it < 2; ++it) {
    int e = it * 256 + tid;
    int d = e >> 3, k8 = (e & 7) * 8;
    u16x8 u;
#pragma unroll
    for (int m = 0; m < 8; ++m)
      u[m] = *(const unsigned short*)&tile[k8 + m][d];
    *(u16x8*)(vrow + (size_t)d * kT + t0 + k8) = u;
  }
}

__device__ inline float gelu_tanh(float c) {
  float t = 0.7978845608028654f * (c + 0.044715f * c * c * c);
  return 0.5f * c * (1.0f + tanhf(t));
}

// ---------------------------------------------------------------------------
// bf16 MFMA GEMM, 128x128 tile, BK=64, 4 waves, 2-phase dbuf (verified r6).
// Used for proj and fc2 (N=768: keeps 384-block utilization).
// ---------------------------------------------------------------------------
template <int OUT_MODE>
__global__ __launch_bounds__(256) void gemm_bf16(
    const __hip_bfloat16* __restrict__ A,   // [M][K] bf16
    const __hip_bfloat16* __restrict__ WT,  // [N][K] bf16
    const float* __restrict__ bias,         // [N] fp32
    const float* __restrict__ R,            // [M][N] fp32 (OUT_MODE 1)
    void* __restrict__ outv, int M, int N, int K)
{
  __shared__ __align__(16) __hip_bfloat16 sh[2][2][128 * 64];  // [buf][A/B]
  const int tid  = threadIdx.x;
  const int lane = tid & 63, wid = tid >> 6;
  const int wr = wid >> 1, wc = wid & 1;
  const int r16 = lane & 15, g = lane >> 4;

  // XCD-aware bijective swizzle (nwg % 8 == 0 for all our grids)
  const int nwg = gridDim.x * gridDim.y;
  const int bid = blockIdx.y * gridDim.x + blockIdx.x;
  const int swz = (bid & 7) * (nwg >> 3) + (bid >> 3);
  const int m0 = (swz / gridDim.x) * 128;
  const int n0 = (swz % gridDim.x) * 128;

  const __hip_bfloat16* Abase = A  + (size_t)m0 * K;
  const __hip_bfloat16* Bbase = WT + (size_t)n0 * K;

  f32x4 acc[4][4] = {};

  auto stage = [&](int t) {
    const int buf = t & 1;
    const __hip_bfloat16* As = Abase + t * 64;
    const __hip_bfloat16* Bs = Bbase + t * 64;
#pragma unroll
    for (int it = 0; it < 4; ++it) {
      int e = it * 256 + tid;                 // chunk id 0..1023
      int row = e >> 3, ch = (e & 7) ^ (row & 7);
      char* la = (char*)&sh[buf][0][0] + (it * 4096 + (tid & ~63) * 16);
      char* lb = (char*)&sh[buf][1][0] + (it * 4096 + (tid & ~63) * 16);
      gload_lds16(As + (size_t)row * K + ch * 8, la);
      gload_lds16(Bs + (size_t)row * K + ch * 8, lb);
    }
  };

  const int NT = K >> 6;
  stage(0);
  __syncthreads();                            // drains vmcnt -> tile 0 ready

  for (int t = 0; t < NT; ++t) {
    const int buf = t & 1;
    if (t + 1 < NT) stage(t + 1);             // in flight during compute
    const char* Ab = (const char*)&sh[buf][0][0];
    const char* Bb = (const char*)&sh[buf][1][0];
#pragma unroll
    for (int s = 0; s < 2; ++s) {             // two k-steps of 32 within BK=64
      bf16x8 af[4], bf[4];
#pragma unroll
      for (int i = 0; i < 4; ++i) {
        int ar = wr * 64 + i * 16 + r16;
        af[i] = *(const bf16x8*)(Ab + ar * 128 + (((s * 4 + g) ^ (ar & 7)) << 4));
        int br = wc * 64 + i * 16 + r16;
        bf[i] = *(const bf16x8*)(Bb + br * 128 + (((s * 4 + g) ^ (br & 7)) << 4));
      }
#pragma unroll
      for (int i = 0; i < 4; ++i)
#pragma unroll
        for (int j = 0; j < 4; ++j)
          acc[i][j] = __builtin_amdgcn_mfma_f32_16x16x32_bf16(af[i], bf[j],
                                                              acc[i][j], 0, 0, 0);
    }
    __syncthreads();   // buf consumed by all waves; next tile fully staged
  }

  const int r0 = m0 + wr * 64 + g * 4;
  const int c0 = n0 + wc * 64 + r16;
#pragma unroll
  for (int i = 0; i < 4; ++i) {
#pragma unroll
    for (int j = 0; j < 4; ++j) {
      int col = c0 + j * 16;
      float bv = bias[col];
#pragma unroll
      for (int q = 0; q < 4; ++q) {
        int row = r0 + i * 16 + q;
        float c = acc[i][j][q] + bv;
        if (OUT_MODE == 1) {
          c += R[(size_t)row * N + col];
          ((float*)outv)[(size_t)row * N + col] = c;
        } else {
          if (OUT_MODE == 2) c = gelu_tanh(c);
          ((__hip_bfloat16*)outv)[(size_t)row * N + col] = __float2bfloat16(c);
        }
      }
    }
  }
}

// ---------------------------------------------------------------------------
// bf16 MFMA GEMM, 256x256 tile, BK=64, 512 threads (8 waves, 2Mx4N), same
// 2-phase dbuf sync structure. Doubles compute per staged byte (wave=128x64
// out, 64 MFMA/K-step). LDS 128KB -> 1 block/CU, 8 waves.
// Used for qkv (288 blocks) and fc (384 blocks).
// ---------------------------------------------------------------------------
template <int OUT_MODE>
__global__ __launch_bounds__(512, 2) void gemm_bf16_256(
    const __hip_bfloat16* __restrict__ A,   // [M][K] bf16
    const __hip_bfloat16* __restrict__ WT,  // [N][K] bf16
    const float* __restrict__ bias,         // [N] fp32
    void* __restrict__ outv, int M, int N, int K)
{
  __shared__ __align__(16) __hip_bfloat16 sh[2][2][256 * 64];  // [buf][A/B] 128KB
  const int tid  = threadIdx.x;
  const int lane = tid & 63, wid = tid >> 6;
  const int wm = wid >> 2, wn = wid & 3;       // 2 x 4 waves
  const int r16 = lane & 15, g = lane >> 4;

  const int nwg = gridDim.x * gridDim.y;
  const int bid = blockIdx.y * gridDim.x + blockIdx.x;
  const int swz = (bid & 7) * (nwg >> 3) + (bid >> 3);
  const int m0 = (swz / gridDim.x) * 256;
  const int n0 = (swz % gridDim.x) * 256;

  const __hip_bfloat16* Abase = A  + (size_t)m0 * K;
  const __hip_bfloat16* Bbase = WT + (size_t)n0 * K;

  f32x4 acc[8][4] = {};

  auto stage = [&](int t) {
    const int buf = t & 1;
    const __hip_bfloat16* As = Abase + t * 64;
    const __hip_bfloat16* Bs = Bbase + t * 64;
#pragma unroll
    for (int it = 0; it < 4; ++it) {
      int e = it * 512 + tid;                 // chunk id 0..2047 (16B each)
      int row = e >> 3, ch = (e & 7) ^ (row & 7);
      char* la = (char*)&sh[buf][0][0] + (it * 8192 + (tid & ~63) * 16);
      char* lb = (char*)&sh[buf][1][0] + (it * 8192 + (tid & ~63) * 16);
      gload_lds16(As + (size_t)row * K + ch * 8, la);
      gload_lds16(Bs + (size_t)row * K + ch * 8, lb);
    }
  };

  const int NT = K >> 6;
  stage(0);
  __syncthreads();

  for (int t = 0; t < NT; ++t) {
    const int buf = t & 1;
    if (t + 1 < NT) stage(t + 1);
    const char* Ab = (const char*)&sh[buf][0][0];
    const char* Bb = (const char*)&sh[buf][1][0];
#pragma unroll
    for (int s = 0; s < 2; ++s) {
      bf16x8 af[8], bf[4];
#pragma unroll
      for (int i = 0; i < 8; ++i) {
        int ar = wm * 128 + i * 16 + r16;
        af[i] = *(const bf16x8*)(Ab + ar * 128 + (((s * 4 + g) ^ (ar & 7)) << 4));
      }
#pragma unroll
      for (int j = 0; j < 4; ++j) {
        int br = wn * 64 + j * 16 + r16;
        bf[j] = *(const bf16x8*)(Bb + br * 128 + (((s * 4 + g) ^ (br & 7)) << 4));
      }
#pragma unroll
      for (int i = 0; i < 8; ++i)
#pragma unroll
        for (int j = 0; j < 4; ++j)
          acc[i][j] = __builtin_amdgcn_mfma_f32_16x16x32_bf16(af[i], bf[j],
                                                              acc[i][j], 0, 0, 0);
    }
    __syncthreads();
  }

  const int r0 = m0 + wm * 128 + g * 4;
  const int c0 = n0 + wn * 64 + r16;
#pragma unroll
  for (int i = 0; i < 8; ++i) {
#pragma unroll
    for (int j = 0; j < 4; ++j) {
      int col = c0 + j * 16;
      float bv = bias[col];
#pragma unroll
      for (int q = 0; q < 4; ++q) {
        int row = r0 + i * 16 + q;
        float c = acc[i][j][q] + bv;
        if (OUT_MODE == 2) c = gelu_tanh(c);
        ((__hip_bfloat16*)outv)[(size_t)row * N + col] = __float2bfloat16(c);
      }
    }
  }
}

// ---------------------------------------------------------------------------
// MFMA flash attention, fixed-shift softmax (verified round 5).
// ---------------------------------------------------------------------------
__global__ __launch_bounds__(256) void attn_mfma(
    const __hip_bfloat16* __restrict__ qkv,
    const __hip_bfloat16* __restrict__ vt,
    const int* __restrict__ mask,
    __hip_bfloat16* __restrict__ o)
{
  __shared__ __align__(16) __hip_bfloat16 Ks[64 * 64];
  __shared__ __align__(16) __hip_bfloat16 Vs[64 * 64];
  __shared__ __align__(16) __hip_bfloat16 Ps[4 * 16 * 64];

  const int b = blockIdx.z, h = blockIdx.y, q0 = blockIdx.x * 64;
  const int tid = threadIdx.x, lane = tid & 63, wid = tid >> 6;
  const int r16 = lane & 15, g = lane >> 4;
  const size_t rs = k3C;
  const __hip_bfloat16* qb = qkv + (size_t)(b * kT) * rs + h * kHD;
  const __hip_bfloat16* kb = qb + kC;
  const __hip_bfloat16* vtb = vt + (size_t)(b * kNH + h) * kHD * kT;
  const int* mrow = mask + b * kT;
  constexpr float kSc = 0.125f * 1.4426950408889634f;  // 0.125 * log2(e)

  bf16x8 qf[2];
  {
    const __hip_bfloat16* qr = qb + (size_t)(q0 + wid * 16 + r16) * rs;
#pragma unroll
    for (int s = 0; s < 2; ++s) qf[s] = *(const bf16x8*)(qr + s * 32 + g * 8);
  }

  f32x4 o_acc[4] = {};          // db: d = 16*db + r16 ; reg: q = g*4 + reg
  float l_part[4] = {0.f, 0.f, 0.f, 0.f};

  __hip_bfloat16* Pw = Ps + wid * 1024;   // per-wave 16x64 tile

  for (int t = 0; t < 16; ++t) {
    __syncthreads();
#pragma unroll
    for (int it = 0; it < 2; ++it) {
      int e = it * 256 + tid;
      int row = e >> 3, ch = (e & 7) ^ (row & 7);
      char* lk = (char*)Ks + (it * 4096 + (tid & ~63) * 16);
      char* lv = (char*)Vs + (it * 4096 + (tid & ~63) * 16);
      gload_lds16(kb + (size_t)(t * 64 + row) * rs + ch * 8, lk);
      gload_lds16(vtb + (size_t)row * kT + t * 64 + ch * 8, lv);
    }
    __syncthreads();

    f32x4 sa[4] = {};
#pragma unroll
    for (int j = 0; j < 4; ++j) {
#pragma unroll
      for (int s = 0; s < 2; ++s) {
        int kr = 16 * j + r16;
        bf16x8 kf = *(const bf16x8*)((const char*)Ks + kr * 128 +
                                     (((s * 4 + g) ^ (kr & 7)) << 4));
        sa[j] = __builtin_amdgcn_mfma_f32_16x16x32_bf16(qf[s], kf, sa[j], 0, 0, 0);
      }
    }

    float keep[4];
#pragma unroll
    for (int j = 0; j < 4; ++j)
      keep[j] = (mrow[t * 64 + 16 * j + r16] != 0) ? 1.f : 0.f;

#pragma unroll
    for (int r = 0; r < 4; ++r) {
      float p[4];
#pragma unroll
      for (int j = 0; j < 4; ++j)
        p[j] = keep[j] != 0.f ? exp2f(sa[j][r] * kSc) : 0.f;
      l_part[r] += (p[0] + p[1]) + (p[2] + p[3]);
      int q = g * 4 + r;
      char* pwq = (char*)Pw + q * 128 + (r16 & 7) * 2;
#pragma unroll
      for (int j = 0; j < 4; ++j) {
        int chn = ((j << 1) | (r16 >> 3)) ^ (q & 7);
        *(__hip_bfloat16*)(pwq + (chn << 4)) = __float2bfloat16(p[j]);
      }
    }

    asm volatile("s_waitcnt lgkmcnt(0)" ::: "memory");  // P writes visible (wave)
    __builtin_amdgcn_sched_barrier(0);

#pragma unroll
    for (int s = 0; s < 2; ++s) {
      bf16x8 pf = *(const bf16x8*)((const char*)Pw + r16 * 128 +
                                   (((s * 4 + g) ^ (r16 & 7)) << 4));
#pragma unroll
      for (int db = 0; db < 4; ++db) {
        int vr = 16 * db + r16;
        bf16x8 vf = *(const bf16x8*)((const char*)Vs + vr * 128 +
                                     (((s * 4 + g) ^ (vr & 7)) << 4));
        o_acc[db] = __builtin_amdgcn_mfma_f32_16x16x32_bf16(pf, vf, o_acc[db], 0, 0, 0);
      }
    }
  }

#pragma unroll
  for (int r = 0; r < 4; ++r) {
    float l = l_part[r];
#pragma unroll
    for (int off = 8; off; off >>= 1) l += __shfl_xor(l, off);
    float inv = 1.f / l;
    size_t row = (size_t)(b * kT) + q0 + wid * 16 + g * 4 + r;
#pragma unroll
    for (int db = 0; db < 4; ++db)
      o[row * kC + h * kHD + 16 * db + r16] = __float2bfloat16(o_acc[db][r] * inv);
  }
}

// ---------------------------------------------------------------------------
// Launch
// ---------------------------------------------------------------------------
extern "C" void kernel_launch(void* const* d_in, const int* in_sizes, int n_in,
                              void* d_out, int out_size, void* d_ws, size_t ws_size,
                              hipStream_t stream) {
  const float* x      = (const float*)d_in[0];
  const int*   amask  = (const int*)  d_in[1];
  const float* ln1_g  = (const float*)d_in[2];
  const float* ln1_b  = (const float*)d_in[3];
  const float* W_attn = (const float*)d_in[4];
  const float* b_attn = (const float*)d_in[5];
  const float* W_proj = (const float*)d_in[6];
  const float* b_proj = (const float*)d_in[7];
  const float* ln2_g  = (const float*)d_in[8];
  const float* ln2_b  = (const float*)d_in[9];
  const float* W_fc   = (const float*)d_in[10];
  const float* b_fc   = (const float*)d_in[11];
  const float* W_fc2  = (const float*)d_in[12];
  const float* b_fc2  = (const float*)d_in[13];
  float* out = (float*)d_out;

  // workspace layout (bytes):
  //   [0, 12.6MB)      h / o / h2  bf16
  //   [16MB, 66.3MB)   qkv bf16 (37.7MB) / fc bf16 (50.3MB) overlay
  //   [68MB..84MB)     transposed bf16 weights
  //   [84MB, 96.6MB)   Vt bf16 [b][h][d][T]
  char* ws = (char*)d_ws;
  __hip_bfloat16* h_bf    = (__hip_bfloat16*)(ws);
  __hip_bfloat16* qkv_bf  = (__hip_bfloat16*)(ws + (size_t)16 * 1024 * 1024);
  __hip_bfloat16* fc_bf   = qkv_bf;
  __hip_bfloat16* wt_attn = (__hip_bfloat16*)(ws + (size_t)68 * 1024 * 1024);
  __hip_bfloat16* wt_proj = (__hip_bfloat16*)(ws + (size_t)72 * 1024 * 1024);
  __hip_bfloat16* wt_fc   = (__hip_bfloat16*)(ws + (size_t)74 * 1024 * 1024);
  __hip_bfloat16* wt_fc2  = (__hip_bfloat16*)(ws + (size_t)79 * 1024 * 1024);
  __hip_bfloat16* vt_bf   = (__hip_bfloat16*)(ws + (size_t)84 * 1024 * 1024);

  dim3 blk(256);
  dim3 blk512(512);

  // 0. weight transpose+cast
  transpose_cast<<<dim3(k3C / 64, kC / 64), blk, 0, stream>>>(W_attn, wt_attn, kC, k3C);
  transpose_cast<<<dim3(kC / 64, kC / 64), blk, 0, stream>>>(W_proj, wt_proj, kC, kC);
  transpose_cast<<<dim3(k4C / 64, kC / 64), blk, 0, stream>>>(W_fc, wt_fc, kC, k4C);
  transpose_cast<<<dim3(kC / 64, k4C / 64), blk, 0, stream>>>(W_fc2, wt_fc2, k4C, kC);

  // 1. h = LN1(x)
  ln_kernel<<<kM, blk, 0, stream>>>(x, ln1_g, ln1_b, h_bf);
  // 2. qkv = h @ W_attn + b_attn   (256x256, 288 blocks)
  gemm_bf16_256<0><<<dim3(k3C / 256, kM / 256), blk512, 0, stream>>>(
      h_bf, wt_attn, b_attn, qkv_bf, kM, k3C, kC);
  // 2b. Vt = transpose(V)
  v_transpose<<<dim3(kT / 64, kNH, kB), blk, 0, stream>>>(qkv_bf, vt_bf);
  // 3. o = attention (overwrites h)
  attn_mfma<<<dim3(kT / 64, kNH, kB), blk, 0, stream>>>(qkv_bf, vt_bf, amask, h_bf);
  // 4. x1 = x + o @ W_proj + b_proj -> d_out (fp32)   (128x128, 384 blocks)
  gemm_bf16<1><<<dim3(kC / 128, kM / 128), blk, 0, stream>>>(
      h_bf, wt_proj, b_proj, x, out, kM, kC, kC);
  // 5. h2 = LN2(x1)
  ln_kernel<<<kM, blk, 0, stream>>>(out, ln2_g, ln2_b, h_bf);
  // 6. fc = gelu(h2 @ W_fc + b_fc)   (256x256, 384 blocks)
  gemm_bf16_256<2><<<dim3(k4C / 256, kM / 256), blk512, 0, stream>>>(
      h_bf, wt_fc, b_fc, fc_bf, kM, k4C, kC);
  // 7. out = x1 + fc @ W_fc2 + b_fc2   (128x128, 384 blocks)
  gemm_bf16<1><<<dim3(kC / 128, kM / 128), blk, 0, stream>>>(
      fc_bf, wt_fc2, b_fc2, out, out, kM, kC, k4C);
}

// Round 8
// 277.941 us; speedup vs baseline: 1.0295x; 1.0295x over previous
//
#include <hip/hip_runtime.h>
#include <hip/hip_bf16.h>
#include <math.h>

// Problem constants
constexpr int kB  = 8;
constexpr int kT  = 1024;
constexpr int kC  = 768;
constexpr int kNH = 12;
constexpr int kHD = 64;
constexpr int kM  = kB * kT;        // 8192 rows
constexpr int k3C = 3 * kC;         // 2304
constexpr int k4C = 4 * kC;         // 3072

typedef __bf16 bf16x8 __attribute__((ext_vector_type(8)));
typedef float  f32x4  __attribute__((ext_vector_type(4)));
typedef unsigned short u16x8 __attribute__((ext_vector_type(8)));

__device__ inline void gload_lds16(const void* g, void* l) {
  // async global->LDS, 16B per lane; LDS dest = wave-uniform base + lane*16
  __builtin_amdgcn_global_load_lds(
      (const __attribute__((address_space(1))) void*)g,
      (__attribute__((address_space(3))) void*)l, 16, 0, 0);
}

// ---------------------------------------------------------------------------
// LayerNorm: one block (256 threads) per row of 768. fp32 in, bf16 out.
// ---------------------------------------------------------------------------
__global__ __launch_bounds__(256) void ln_kernel(
    const float* __restrict__ x, const float* __restrict__ g,
    const float* __restrict__ bta, __hip_bfloat16* __restrict__ out)
{
  __shared__ float red[4];
  int row = blockIdx.x;
  int tid = threadIdx.x;
  const float* xr = x + (size_t)row * kC;
  float v0 = xr[tid], v1 = xr[tid + 256], v2 = xr[tid + 512];

  float s = v0 + v1 + v2;
#pragma unroll
  for (int off = 32; off; off >>= 1) s += __shfl_xor(s, off);
  if ((tid & 63) == 0) red[tid >> 6] = s;
  __syncthreads();
  float mu = (red[0] + red[1] + red[2] + red[3]) * (1.0f / kC);

  float d0 = v0 - mu, d1 = v1 - mu, d2 = v2 - mu;
  float q = d0 * d0 + d1 * d1 + d2 * d2;
#pragma unroll
  for (int off = 32; off; off >>= 1) q += __shfl_xor(q, off);
  __syncthreads();
  if ((tid & 63) == 0) red[tid >> 6] = q;
  __syncthreads();
  float var = (red[0] + red[1] + red[2] + red[3]) * (1.0f / kC);
  float inv = rsqrtf(var + 1e-5f);

  __hip_bfloat16* orow = out + (size_t)row * kC;
  orow[tid]       = __float2bfloat16(d0 * inv * g[tid]       + bta[tid]);
  orow[tid + 256] = __float2bfloat16(d1 * inv * g[tid + 256] + bta[tid + 256]);
  orow[tid + 512] = __float2bfloat16(d2 * inv * g[tid + 512] + bta[tid + 512]);
}

// ---------------------------------------------------------------------------
// Weight transpose + cast: W[K][N] fp32 -> WT[N][K] bf16. 64x64 tiles.
// ---------------------------------------------------------------------------
__global__ __launch_bounds__(256) void transpose_cast(
    const float* __restrict__ W, __hip_bfloat16* __restrict__ WT, int K, int N)
{
  __shared__ __hip_bfloat16 t[64][65];
  int k0 = blockIdx.y * 64, n0 = blockIdx.x * 64;
  int tid = threadIdx.x;
#pragma unroll
  for (int it = 0; it < 16; ++it) {
    int e = it * 256 + tid;
    int r = e >> 6, c = e & 63;
    t[r][c] = __float2bfloat16(W[(size_t)(k0 + r) * N + n0 + c]);
  }
  __syncthreads();
#pragma unroll
  for (int it = 0; it < 16; ++it) {
    int e = it * 256 + tid;
    int nr = e >> 6, kc = e & 63;
    WT[(size_t)(n0 + nr) * K + k0 + kc] = t[kc][nr];
  }
}

// ---------------------------------------------------------------------------
// V transpose: qkv V-part [b][t][h][d] -> Vt[b][h][d][t]  (bf16)
// ---------------------------------------------------------------------------
__global__ __launch_bounds__(256) void v_transpose(
    const __hip_bfloat16* __restrict__ qkv, __hip_bfloat16* __restrict__ vt)
{
  __shared__ __hip_bfloat16 tile[64][80];   // row stride 160B (16B-aligned)
  int b = blockIdx.z, h = blockIdx.y, t0 = blockIdx.x * 64;
  int tid = threadIdx.x;
  const __hip_bfloat16* vb = qkv + (size_t)(b * kT) * k3C + 2 * kC + h * kHD;
#pragma unroll
  for (int it = 0; it < 2; ++it) {
    int e = it * 256 + tid;
    int r = e >> 3, c8 = (e & 7) * 8;
    *(u16x8*)&tile[r][c8] = *(const u16x8*)(vb + (size_t)(t0 + r) * k3C + c8);
  }
  __syncthreads();
  __hip_bfloat16* vrow = vt + (size_t)(b * kNH + h) * kHD * kT;
#pragma unroll
  for (int it = 0; it < 2; ++it) {
    int e = it * 256 + tid;
    int d = e >> 3, k8 = (e & 7) * 8;
    u16x8 u;
#pragma unroll
    for (int m = 0; m < 8; ++m)
      u[m] = *(const unsigned short*)&tile[k8 + m][d];
    *(u16x8*)(vrow + (size_t)d * kT + t0 + k8) = u;
  }
}

__device__ inline float gelu_tanh(float c) {
  float t = 0.7978845608028654f * (c + 0.044715f * c * c * c);
  return 0.5f * c * (1.0f + tanhf(t));
}

// ---------------------------------------------------------------------------
// bf16 MFMA GEMM, 128xBN tile (BN=128 or 96), BK=64, 4 waves (2x2),
// 2-phase dbuf (verified r6). BN=96 makes proj/fc2 grids exactly 512 blocks
// (= 2 blocks/CU x 256 CUs, no dispatch tail). Full 8-chunk XOR involution
// on stage-source and ds_read (0 bank conflicts, verified). XCD swizzle.
// ---------------------------------------------------------------------------
template <int OUT_MODE, int BN>
__global__ __launch_bounds__(256) void gemm_bf16(
    const __hip_bfloat16* __restrict__ A,   // [M][K] bf16
    const __hip_bfloat16* __restrict__ WT,  // [N][K] bf16
    const float* __restrict__ bias,         // [N] fp32
    const float* __restrict__ R,            // [M][N] fp32 (OUT_MODE 1)
    void* __restrict__ outv, int M, int N, int K)
{
  constexpr int NJ = BN / 32;               // B-frags per wave (4 or 3)
  __shared__ __align__(16) __hip_bfloat16 As[2][128 * 64];
  __shared__ __align__(16) __hip_bfloat16 Bs[2][BN * 64];
  const int tid  = threadIdx.x;
  const int lane = tid & 63, wid = tid >> 6;
  const int wr = wid >> 1, wc = wid & 1;
  const int r16 = lane & 15, g = lane >> 4;

  // XCD-aware bijective swizzle (nwg % 8 == 0 for all our grids)
  const int nwg = gridDim.x * gridDim.y;
  const int bid = blockIdx.y * gridDim.x + blockIdx.x;
  const int swz = (bid & 7) * (nwg >> 3) + (bid >> 3);
  const int m0 = (swz / gridDim.x) * 128;
  const int n0 = (swz % gridDim.x) * BN;

  const __hip_bfloat16* Abase = A  + (size_t)m0 * K;
  const __hip_bfloat16* Bbase = WT + (size_t)n0 * K;

  f32x4 acc[4][NJ] = {};

  auto stage = [&](int t) {
    const int buf = t & 1;
    const __hip_bfloat16* Ap = Abase + t * 64;
    const __hip_bfloat16* Bp = Bbase + t * 64;
#pragma unroll
    for (int it = 0; it < 4; ++it) {        // A: 128 rows x 8 chunks
      int e = it * 256 + tid;
      int row = e >> 3, ch = (e & 7) ^ (row & 7);
      char* la = (char*)&As[buf][0] + (it * 4096 + (tid & ~63) * 16);
      gload_lds16(Ap + (size_t)row * K + ch * 8, la);
    }
#pragma unroll
    for (int it = 0; it < BN / 32; ++it) {  // B: BN rows x 8 chunks
      int e = it * 256 + tid;
      int row = e >> 3, ch = (e & 7) ^ (row & 7);
      char* lb = (char*)&Bs[buf][0] + (it * 4096 + (tid & ~63) * 16);
      gload_lds16(Bp + (size_t)row * K + ch * 8, lb);
    }
  };

  const int NT = K >> 6;
  stage(0);
  __syncthreads();                          // drains vmcnt -> tile 0 ready

  for (int t = 0; t < NT; ++t) {
    const int buf = t & 1;
    if (t + 1 < NT) stage(t + 1);           // in flight during compute
    const char* Ab = (const char*)&As[buf][0];
    const char* Bb = (const char*)&Bs[buf][0];
#pragma unroll
    for (int s = 0; s < 2; ++s) {           // two k-steps of 32 within BK=64
      bf16x8 af[4], bf[NJ];
#pragma unroll
      for (int i = 0; i < 4; ++i) {
        int ar = wr * 64 + i * 16 + r16;
        af[i] = *(const bf16x8*)(Ab + ar * 128 + (((s * 4 + g) ^ (ar & 7)) << 4));
      }
#pragma unroll
      for (int j = 0; j < NJ; ++j) {
        int br = wc * (BN / 2) + j * 16 + r16;
        bf[j] = *(const bf16x8*)(Bb + br * 128 + (((s * 4 + g) ^ (br & 7)) << 4));
      }
#pragma unroll
      for (int i = 0; i < 4; ++i)
#pragma unroll
        for (int j = 0; j < NJ; ++j)
          acc[i][j] = __builtin_amdgcn_mfma_f32_16x16x32_bf16(af[i], bf[j],
                                                              acc[i][j], 0, 0, 0);
    }
    __syncthreads();   // buf consumed by all waves; next tile fully staged
  }

  // epilogue: C/D layout col=lane&15, row=(lane>>4)*4+reg  [m89-verified]
  const int r0 = m0 + wr * 64 + g * 4;
  const int c0 = n0 + wc * (BN / 2) + r16;
#pragma unroll
  for (int i = 0; i < 4; ++i) {
#pragma unroll
    for (int j = 0; j < NJ; ++j) {
      int col = c0 + j * 16;
      float bv = bias[col];
#pragma unroll
      for (int q = 0; q < 4; ++q) {
        int row = r0 + i * 16 + q;
        float c = acc[i][j][q] + bv;
        if (OUT_MODE == 1) {
          c += R[(size_t)row * N + col];
          ((float*)outv)[(size_t)row * N + col] = c;
        } else {
          if (OUT_MODE == 2) c = gelu_tanh(c);
          ((__hip_bfloat16*)outv)[(size_t)row * N + col] = __float2bfloat16(c);
        }
      }
    }
  }
}

// ---------------------------------------------------------------------------
// MFMA flash attention, fixed-shift softmax (verified round 5).
// ---------------------------------------------------------------------------
__global__ __launch_bounds__(256) void attn_mfma(
    const __hip_bfloat16* __restrict__ qkv,
    const __hip_bfloat16* __restrict__ vt,
    const int* __restrict__ mask,
    __hip_bfloat16* __restrict__ o)
{
  __shared__ __align__(16) __hip_bfloat16 Ks[64 * 64];
  __shared__ __align__(16) __hip_bfloat16 Vs[64 * 64];
  __shared__ __align__(16) __hip_bfloat16 Ps[4 * 16 * 64];

  const int b = blockIdx.z, h = blockIdx.y, q0 = blockIdx.x * 64;
  const int tid = threadIdx.x, lane = tid & 63, wid = tid >> 6;
  const int r16 = lane & 15, g = lane >> 4;
  const size_t rs = k3C;
  const __hip_bfloat16* qb = qkv + (size_t)(b * kT) * rs + h * kHD;
  const __hip_bfloat16* kb = qb + kC;
  const __hip_bfloat16* vtb = vt + (size_t)(b * kNH + h) * kHD * kT;
  const int* mrow = mask + b * kT;
  constexpr float kSc = 0.125f * 1.4426950408889634f;  // 0.125 * log2(e)

  bf16x8 qf[2];
  {
    const __hip_bfloat16* qr = qb + (size_t)(q0 + wid * 16 + r16) * rs;
#pragma unroll
    for (int s = 0; s < 2; ++s) qf[s] = *(const bf16x8*)(qr + s * 32 + g * 8);
  }

  f32x4 o_acc[4] = {};          // db: d = 16*db + r16 ; reg: q = g*4 + reg
  float l_part[4] = {0.f, 0.f, 0.f, 0.f};

  __hip_bfloat16* Pw = Ps + wid * 1024;   // per-wave 16x64 tile

  for (int t = 0; t < 16; ++t) {
    __syncthreads();
#pragma unroll
    for (int it = 0; it < 2; ++it) {
      int e = it * 256 + tid;
      int row = e >> 3, ch = (e & 7) ^ (row & 7);
      char* lk = (char*)Ks + (it * 4096 + (tid & ~63) * 16);
      char* lv = (char*)Vs + (it * 4096 + (tid & ~63) * 16);
      gload_lds16(kb + (size_t)(t * 64 + row) * rs + ch * 8, lk);
      gload_lds16(vtb + (size_t)row * kT + t * 64 + ch * 8, lv);
    }
    __syncthreads();

    f32x4 sa[4] = {};
#pragma unroll
    for (int j = 0; j < 4; ++j) {
#pragma unroll
      for (int s = 0; s < 2; ++s) {
        int kr = 16 * j + r16;
        bf16x8 kf = *(const bf16x8*)((const char*)Ks + kr * 128 +
                                     (((s * 4 + g) ^ (kr & 7)) << 4));
        sa[j] = __builtin_amdgcn_mfma_f32_16x16x32_bf16(qf[s], kf, sa[j], 0, 0, 0);
      }
    }

    float keep[4];
#pragma unroll
    for (int j = 0; j < 4; ++j)
      keep[j] = (mrow[t * 64 + 16 * j + r16] != 0) ? 1.f : 0.f;

#pragma unroll
    for (int r = 0; r < 4; ++r) {
      float p[4];
#pragma unroll
      for (int j = 0; j < 4; ++j)
        p[j] = keep[j] != 0.f ? exp2f(sa[j][r] * kSc) : 0.f;
      l_part[r] += (p[0] + p[1]) + (p[2] + p[3]);
      int q = g * 4 + r;
      char* pwq = (char*)Pw + q * 128 + (r16 & 7) * 2;
#pragma unroll
      for (int j = 0; j < 4; ++j) {
        int chn = ((j << 1) | (r16 >> 3)) ^ (q & 7);
        *(__hip_bfloat16*)(pwq + (chn << 4)) = __float2bfloat16(p[j]);
      }
    }

    asm volatile("s_waitcnt lgkmcnt(0)" ::: "memory");  // P writes visible (wave)
    __builtin_amdgcn_sched_barrier(0);

#pragma unroll
    for (int s = 0; s < 2; ++s) {
      bf16x8 pf = *(const bf16x8*)((const char*)Pw + r16 * 128 +
                                   (((s * 4 + g) ^ (r16 & 7)) << 4));
#pragma unroll
      for (int db = 0; db < 4; ++db) {
        int vr = 16 * db + r16;
        bf16x8 vf = *(const bf16x8*)((const char*)Vs + vr * 128 +
                                     (((s * 4 + g) ^ (vr & 7)) << 4));
        o_acc[db] = __builtin_amdgcn_mfma_f32_16x16x32_bf16(pf, vf, o_acc[db], 0, 0, 0);
      }
    }
  }

#pragma unroll
  for (int r = 0; r < 4; ++r) {
    float l = l_part[r];
#pragma unroll
    for (int off = 8; off; off >>= 1) l += __shfl_xor(l, off);
    float inv = 1.f / l;
    size_t row = (size_t)(b * kT) + q0 + wid * 16 + g * 4 + r;
#pragma unroll
    for (int db = 0; db < 4; ++db)
      o[row * kC + h * kHD + 16 * db + r16] = __float2bfloat16(o_acc[db][r] * inv);
  }
}

// ---------------------------------------------------------------------------
// Launch
// ---------------------------------------------------------------------------
extern "C" void kernel_launch(void* const* d_in, const int* in_sizes, int n_in,
                              void* d_out, int out_size, void* d_ws, size_t ws_size,
                              hipStream_t stream) {
  const float* x      = (const float*)d_in[0];
  const int*   amask  = (const int*)  d_in[1];
  const float* ln1_g  = (const float*)d_in[2];
  const float* ln1_b  = (const float*)d_in[3];
  const float* W_attn = (const float*)d_in[4];
  const float* b_attn = (const float*)d_in[5];
  const float* W_proj = (const float*)d_in[6];
  const float* b_proj = (const float*)d_in[7];
  const float* ln2_g  = (const float*)d_in[8];
  const float* ln2_b  = (const float*)d_in[9];
  const float* W_fc   = (const float*)d_in[10];
  const float* b_fc   = (const float*)d_in[11];
  const float* W_fc2  = (const float*)d_in[12];
  const float* b_fc2  = (const float*)d_in[13];
  float* out = (float*)d_out;

  // workspace layout (bytes):
  //   [0, 12.6MB)      h / o / h2  bf16
  //   [16MB, 66.3MB)   qkv bf16 (37.7MB) / fc bf16 (50.3MB) overlay
  //   [68MB..84MB)     transposed bf16 weights
  //   [84MB, 96.6MB)   Vt bf16 [b][h][d][T]
  char* ws = (char*)d_ws;
  __hip_bfloat16* h_bf    = (__hip_bfloat16*)(ws);
  __hip_bfloat16* qkv_bf  = (__hip_bfloat16*)(ws + (size_t)16 * 1024 * 1024);
  __hip_bfloat16* fc_bf   = qkv_bf;
  __hip_bfloat16* wt_attn = (__hip_bfloat16*)(ws + (size_t)68 * 1024 * 1024);
  __hip_bfloat16* wt_proj = (__hip_bfloat16*)(ws + (size_t)72 * 1024 * 1024);
  __hip_bfloat16* wt_fc   = (__hip_bfloat16*)(ws + (size_t)74 * 1024 * 1024);
  __hip_bfloat16* wt_fc2  = (__hip_bfloat16*)(ws + (size_t)79 * 1024 * 1024);
  __hip_bfloat16* vt_bf   = (__hip_bfloat16*)(ws + (size_t)84 * 1024 * 1024);

  dim3 blk(256);

  // 0. weight transpose+cast
  transpose_cast<<<dim3(k3C / 64, kC / 64), blk, 0, stream>>>(W_attn, wt_attn, kC, k3C);
  transpose_cast<<<dim3(kC / 64, kC / 64), blk, 0, stream>>>(W_proj, wt_proj, kC, kC);
  transpose_cast<<<dim3(k4C / 64, kC / 64), blk, 0, stream>>>(W_fc, wt_fc, kC, k4C);
  transpose_cast<<<dim3(kC / 64, k4C / 64), blk, 0, stream>>>(W_fc2, wt_fc2, k4C, kC);

  // 1. h = LN1(x)
  ln_kernel<<<kM, blk, 0, stream>>>(x, ln1_g, ln1_b, h_bf);
  // 2. qkv = h @ W_attn + b_attn   (128x128, 18x64 = 1152 blocks)
  gemm_bf16<0, 128><<<dim3(k3C / 128, kM / 128), blk, 0, stream>>>(
      h_bf, wt_attn, b_attn, nullptr, qkv_bf, kM, k3C, kC);
  // 2b. Vt = transpose(V)
  v_transpose<<<dim3(kT / 64, kNH, kB), blk, 0, stream>>>(qkv_bf, vt_bf);
  // 3. o = attention (overwrites h)
  attn_mfma<<<dim3(kT / 64, kNH, kB), blk, 0, stream>>>(qkv_bf, vt_bf, amask, h_bf);
  // 4. x1 = x + o @ W_proj + b_proj -> d_out (fp32)   (128x96, 8x64 = 512 blocks)
  gemm_bf16<1, 96><<<dim3(kC / 96, kM / 128), blk, 0, stream>>>(
      h_bf, wt_proj, b_proj, x, out, kM, kC, kC);
  // 5. h2 = LN2(x1)
  ln_kernel<<<kM, blk, 0, stream>>>(out, ln2_g, ln2_b, h_bf);
  // 6. fc = gelu(h2 @ W_fc + b_fc)   (128x128, 24x64 = 1536 blocks)
  gemm_bf16<2, 128><<<dim3(k4C / 128, kM / 128), blk, 0, stream>>>(
      h_bf, wt_fc, b_fc, nullptr, fc_bf, kM, k4C, kC);
  // 7. out = x1 + fc @ W_fc2 + b_fc2   (128x96, 8x64 = 512 blocks)
  gemm_bf16<1, 96><<<dim3(kC / 96, kM / 128), blk, 0, stream>>>(
      fc_bf, wt_fc2, b_fc2, out, out, kM, kC, k4C);
}